// Round 6
// baseline (277.114 us; speedup 1.0000x reference)
//
#include <hip/hip_runtime.h>
#include <stdint.h>
#include <stddef.h>

#define CDIM 1024
#define HWD  1024   // 32*32
#define TD   16
#define BD   2
#define NH   16
#define DHD  64

typedef __attribute__((ext_vector_type(8))) short bf16x8;
typedef __attribute__((ext_vector_type(4))) short bf16x4;
typedef __attribute__((ext_vector_type(4))) float f32x4;

static __device__ __forceinline__ short f2bf(float f) {
  uint32_t u = __builtin_bit_cast(uint32_t, f);
  uint32_t r = (u + 0x7FFFu + ((u >> 16) & 1u)) >> 16;
  return (short)(uint16_t)r;
}
static __device__ __forceinline__ float bf2f(short s) {
  return __builtin_bit_cast(float, (uint32_t)((uint16_t)s) << 16);
}

static __device__ __forceinline__ void gl_lds16(const short* g, short* l) {
  __builtin_amdgcn_global_load_lds((const __attribute__((address_space(1))) unsigned int*)g,
                                   (__attribute__((address_space(3))) unsigned int*)l,
                                   16, 0, 0);
}

// ---------------- K0: cast f32 -> bf16 (used for Wv, Wq, Wk) ----------------
__global__ void k_cast_w(const float* __restrict__ W, short* __restrict__ Wb) {
  int i = (blockIdx.x * 256 + threadIdx.x) * 4;
  f32x4 v = *(const f32x4*)&W[i];
  Wb[i + 0] = f2bf(v[0]);
  Wb[i + 1] = f2bf(v[1]);
  Wb[i + 2] = f2bf(v[2]);
  Wb[i + 3] = f2bf(v[3]);
}

// ---------------- K1: LayerNorm over C + transposed bf16 write + pool partials ----
// v2: 16-pixel blocks, grid (64, 32) = 2048 blocks -> 8 blocks/CU occupancy.
// Thread = (pg 0..3 [4 px], cs 0..63). Block's x slice (64 KB) is L2-resident
// between pass 1 and pass 2.
__global__ __launch_bounds__(256) void k_ln_t(const float* __restrict__ x,
                                              const float* __restrict__ lnw,
                                              const float* __restrict__ lnb,
                                              short* __restrict__ xnT,
                                              float* __restrict__ part) {
  int bt = blockIdx.y;
  int p0 = blockIdx.x * 16;
  int tid = threadIdx.x;
  int pg = tid & 3, cs = tid >> 2;
  int pbase = p0 + pg * 4;
  const float* xs = x + (size_t)bt * CDIM * HWD;

  // ---- pass 1: per-pixel sum / sumsq over C
  float s[4] = {}, s2[4] = {};
  #pragma unroll
  for (int j = 0; j < 16; ++j) {
    int c = cs + 64 * j;
    f32x4 v = *(const f32x4*)&xs[(size_t)c * HWD + pbase];
    #pragma unroll
    for (int i = 0; i < 4; ++i) { s[i] += v[i]; s2[i] += v[i] * v[i]; }
  }
  __shared__ float redA[64][16], redB[64][16];
  #pragma unroll
  for (int i = 0; i < 4; ++i) {
    redA[cs][pg * 4 + i] = s[i];
    redB[cs][pg * 4 + i] = s2[i];
  }
  __syncthreads();
  __shared__ float muS[16], rsS[16];
  if (tid < 16) {
    float a = 0.f, b2 = 0.f;
    for (int k = 0; k < 64; ++k) { a += redA[k][tid]; b2 += redB[k][tid]; }
    float mu = a * (1.0f / CDIM);
    float var = b2 * (1.0f / CDIM) - mu * mu;
    muS[tid] = mu;
    rsS[tid] = rsqrtf(var + 1e-5f);
  }
  __syncthreads();
  float mu_[4], rs_[4];
  #pragma unroll
  for (int i = 0; i < 4; ++i) { mu_[i] = muS[pg * 4 + i]; rs_[i] = rsS[pg * 4 + i]; }

  // ---- pass 2: normalize (L2-hit), transpose via LDS, pool partials
  __shared__ short tile[16 * 272];     // [16 px][256 c] padded to 272 (16B-aligned rows)
  __shared__ float pr[256][4];
  short* outB = xnT + (size_t)bt * CDIM * HWD;

  for (int cb = 0; cb < 4; ++cb) {
    #pragma unroll
    for (int jj = 0; jj < 4; ++jj) {
      int cl = cs * 4 + jj;
      int c = cb * 256 + cl;
      f32x4 v = *(const f32x4*)&xs[(size_t)c * HWD + pbase];
      float w = lnw[c], bb = lnb[c];
      float psum = 0.f;
      #pragma unroll
      for (int i = 0; i < 4; ++i) {
        float xn = (v[i] - mu_[i]) * rs_[i] * w + bb;
        tile[(pg * 4 + i) * 272 + cl] = f2bf(xn);
        psum += xn;
      }
      pr[cl][pg] = psum;
    }
    __syncthreads();
    // transposed global write: 512 chunks of 16 B
    #pragma unroll
    for (int it = 0; it < 2; ++it) {
      int ch = it * 256 + tid;
      int plo = ch >> 5;            // 0..15
      int c8 = (ch & 31) * 8;       // 0..248
      bf16x8 vv = *(const bf16x8*)&tile[plo * 272 + c8];
      int pq = p0 + plo;
      int q = (pq & 31) * 32 + (pq >> 5);   // 32x32 spatial transpose
      *(bf16x8*)&outB[(size_t)q * CDIM + cb * 256 + c8] = vv;
    }
    // pool partial for this c-block
    {
      float a = pr[tid][0] + pr[tid][1] + pr[tid][2] + pr[tid][3];
      part[((size_t)bt * 64 + blockIdx.x) * CDIM + cb * 256 + tid] = a;
    }
    __syncthreads();
  }
}

// ---------------- K2: pooled(bf16) = mean over pixels (reduce 64 partials) ------
__global__ void k_pool_red(const float* __restrict__ part, short* __restrict__ pooledb) {
  int bt = blockIdx.y;
  int c = blockIdx.x * 256 + threadIdx.x;
  float s = 0.f;
  #pragma unroll
  for (int pc = 0; pc < 64; ++pc) s += part[((size_t)bt * 64 + pc) * CDIM + c];
  pooledb[bt * CDIM + c] = f2bf(s * (1.0f / HWD));
}

// ---------------- K3: q|k = pooled @ [Wq;Wk]^T via MFMA ----------------
__global__ __launch_bounds__(256) void k_qk_mfma(const short* __restrict__ Wqkb,
                                                 const short* __restrict__ pooledb,
                                                 float* __restrict__ qm,
                                                 float* __restrict__ km) {
  int n0 = blockIdx.x * 128;
  __shared__ __align__(16) short lA[32 * 32];
  __shared__ __align__(16) short lB[128 * 32];
  int tid = threadIdx.x, lane = tid & 63, wid = tid >> 6;
  int s0 = wid * 128 + lane, s1 = s0 + 64;
  int fr = lane & 15, fk = (lane >> 4) * 8;
  f32x4 acc[2][2] = {};

  for (int kt = 0; kt < CDIM / 32; ++kt) {
    int k0 = kt * 32;
    __syncthreads();
    gl_lds16(&Wqkb[(size_t)(n0 + (s0 >> 2)) * CDIM + k0 + (s0 & 3) * 8], &lB[s0 * 8]);
    gl_lds16(&Wqkb[(size_t)(n0 + (s1 >> 2)) * CDIM + k0 + (s1 & 3) * 8], &lB[s1 * 8]);
    if (wid < 2) {
      gl_lds16(&pooledb[(size_t)(tid >> 2) * CDIM + k0 + (tid & 3) * 8], &lA[tid * 8]);
    }
    __syncthreads();
    bf16x8 af[2], bfr[2];
    #pragma unroll
    for (int mi = 0; mi < 2; ++mi)
      af[mi] = *(const bf16x8*)&lA[(mi * 16 + fr) * 32 + fk];
    #pragma unroll
    for (int ni = 0; ni < 2; ++ni)
      bfr[ni] = *(const bf16x8*)&lB[(wid * 32 + ni * 16 + fr) * 32 + fk];
    #pragma unroll
    for (int mi = 0; mi < 2; ++mi)
      #pragma unroll
      for (int ni = 0; ni < 2; ++ni)
        acc[mi][ni] = __builtin_amdgcn_mfma_f32_16x16x32_bf16(af[mi], bfr[ni], acc[mi][ni], 0, 0, 0);
  }

  int cr = lane >> 4;
  #pragma unroll
  for (int mi = 0; mi < 2; ++mi)
    #pragma unroll
    for (int ni = 0; ni < 2; ++ni)
      #pragma unroll
      for (int rr = 0; rr < 4; ++rr) {
        int row = mi * 16 + cr * 4 + rr;
        int col = n0 + wid * 32 + ni * 16 + fr;
        float v = acc[mi][ni][rr];
        if (col < 1024) qm[(size_t)row * CDIM + col] = v;
        else            km[(size_t)row * CDIM + col - 1024] = v;
      }
}

// ---------------- K4: attention softmax ----------------
__global__ void k_attn(const float* __restrict__ qm, const float* __restrict__ km,
                       float* __restrict__ attn) {
  int bg = blockIdx.x;
  int b = bg >> 4, g = bg & 15;
  int s = threadIdx.x >> 4, t = threadIdx.x & 15;
  const float* qr = qm + (size_t)(b * TD + s) * CDIM + g * DHD;
  const float* kr = km + (size_t)(b * TD + t) * CDIM + g * DHD;
  float d = 0.f;
  #pragma unroll
  for (int i = 0; i < DHD; ++i) d += qr[i] * kr[i];
  d *= 0.125f;
  float m = d;
  #pragma unroll
  for (int off = 8; off; off >>= 1) m = fmaxf(m, __shfl_xor(m, off, 16));
  float e = __expf(d - m);
  float sum = e;
  #pragma unroll
  for (int off = 8; off; off >>= 1) sum += __shfl_xor(sum, off, 16);
  attn[(size_t)bg * 256 + s * 16 + t] = e / sum;
}

// ---------------- K5: V-GEMM v4 -----------------------------------------------
// vp[bt][c][q] = sum_c' Wv[c,c'] * xnT[bt][q][c']
// 256x256 tile, BK=32, TRIPLE-buffered LDS (96 KB), 8 waves (2M x 4N),
// 2 phases/K-tile (16 MFMA each). Staggered prefetch DEPTH-2: each phase
// issues half of tile kt+2; counted vmcnt(6) once per tile (m218 formula
// N = 2 loads/half x 3 halves in flight). Swizzle for BK=32: physical chunk
// = klane ^ ((row>>1)&3), applied on global source AND ds_read (rule #21).
__global__ __launch_bounds__(512, 2) void k_vgemm(const short* __restrict__ Wb,
                                                  const short* __restrict__ xnT,
                                                  short* __restrict__ vp) {
  const int NT = CDIM / 32;  // 32 K-tiles
  int bid = blockIdx.x;
  int swz = (bid & 7) * 64 + (bid >> 3);   // bijective XCD swizzle (512%8==0)
  int bt = swz >> 4;
  int m0 = ((swz >> 2) & 3) * 256;
  int n0 = (swz & 3) * 256;
  const short* Bm = xnT + (size_t)bt * CDIM * HWD;

  __shared__ __align__(16) short lA[3][256 * 32];   // 3 x 16 KB
  __shared__ __align__(16) short lB[3][256 * 32];   // 3 x 16 KB

  int tid = threadIdx.x, l = tid & 63, w = tid >> 6;
  int wm = w >> 2, wn = w & 3;   // wave tile: 128(M) x 64(N)

  // staging: slot = g*512 + w*64 + l; row = g*128 + w*16 + (l>>2); pchunk = l&3
  // source logical chunk lc = (l&3) ^ ((l>>3)&3)  [== pchunk ^ ((row>>1)&3)]
  int rowoff = w * 16 + (l >> 2);
  int lc8 = ((l & 3) ^ ((l >> 3) & 3)) * 8;
  const short* gA = Wb + (size_t)(m0 + rowoff) * CDIM + lc8;
  const short* gB = Bm + (size_t)(n0 + rowoff) * CDIM + lc8;
  int ldsoff = (w * 64 + l) * 8;   // shorts

  // fragment reads: logical chunk klane lives at physical klane ^ ((fr>>1)&3)
  int fr = l & 15, klane = l >> 4;
  int c0 = (klane ^ ((fr >> 1) & 3)) * 8;
  int rA = (wm * 128 + fr) * 32;
  int rB = (wn * 64 + fr) * 32;

  f32x4 acc[8][4] = {};
  bf16x8 bq[4], af[4];

#define ISSUE(g, kt2, bf)                                                          \
  do {                                                                             \
    gl_lds16(gA + (size_t)(g) * 128 * CDIM + (kt2) * 32, &lA[bf][(g) * 4096 + ldsoff]); \
    gl_lds16(gB + (size_t)(g) * 128 * CDIM + (kt2) * 32, &lB[bf][(g) * 4096 + ldsoff]); \
  } while (0)
#define RDA(mi, bf) (*(const bf16x8*)&lA[bf][rA + (mi) * 512 + c0])
#define RDB(ni, bf) (*(const bf16x8*)&lB[bf][rB + (ni) * 512 + c0])

  // prologue: stage tiles 0 and 1
  ISSUE(0, 0, 0); ISSUE(1, 0, 0);
  ISSUE(0, 1, 1); ISSUE(1, 1, 1);

  for (int kt = 0; kt < NT; ++kt) {
    int cb = kt % 3;
    int pb = (kt + 2) % 3;
    // ---- phase 0 (mi 0-3): prefetch g0 of kt+2, rendezvous on tile kt
    if (kt + 2 < NT) ISSUE(0, kt + 2, pb);
    if (kt < NT - 2)       asm volatile("s_waitcnt vmcnt(6)" ::: "memory");
    else if (kt == NT - 2) asm volatile("s_waitcnt vmcnt(4)" ::: "memory");
    else                   asm volatile("s_waitcnt vmcnt(0)" ::: "memory");
    __builtin_amdgcn_s_barrier();
    #pragma unroll
    for (int ni = 0; ni < 4; ++ni) bq[ni] = RDB(ni, cb);
    #pragma unroll
    for (int mi = 0; mi < 4; ++mi) af[mi] = RDA(mi, cb);
    __builtin_amdgcn_s_setprio(1);
    #pragma unroll
    for (int mi = 0; mi < 4; ++mi)
      #pragma unroll
      for (int ni = 0; ni < 4; ++ni)
        acc[mi][ni] = __builtin_amdgcn_mfma_f32_16x16x32_bf16(af[mi], bq[ni], acc[mi][ni], 0, 0, 0);
    __builtin_amdgcn_s_setprio(0);
    __builtin_amdgcn_s_barrier();
    // ---- phase 1 (mi 4-7): prefetch g1 of kt+2
    if (kt + 2 < NT) ISSUE(1, kt + 2, pb);
    #pragma unroll
    for (int mi = 0; mi < 4; ++mi) af[mi] = RDA(4 + mi, cb);
    __builtin_amdgcn_s_barrier();
    __builtin_amdgcn_s_setprio(1);
    #pragma unroll
    for (int mi = 0; mi < 4; ++mi)
      #pragma unroll
      for (int ni = 0; ni < 4; ++ni)
        acc[4 + mi][ni] = __builtin_amdgcn_mfma_f32_16x16x32_bf16(af[mi], bq[ni], acc[4 + mi][ni], 0, 0, 0);
    __builtin_amdgcn_s_setprio(0);
    __builtin_amdgcn_s_barrier();
  }
#undef ISSUE
#undef RDA
#undef RDB

  short* outB = vp + (size_t)bt * CDIM * HWD;
  int cr = l >> 4;
  #pragma unroll
  for (int mi = 0; mi < 8; ++mi)
    #pragma unroll
    for (int ni = 0; ni < 4; ++ni)
      #pragma unroll
      for (int r = 0; r < 4; ++r) {
        int row = m0 + wm * 128 + mi * 16 + cr * 4 + r;   // c
        int col = n0 + wn * 64 + ni * 16 + fr;            // q
        outB[(size_t)row * HWD + col] = f2bf(acc[mi][ni][r]);
      }
}

// ---------------- K6: T-mix ----------------
__global__ __launch_bounds__(256) void k_mix(const short* __restrict__ vp,
                                             const float* __restrict__ attn,
                                             float* __restrict__ out) {
  int c = blockIdx.x;
  int b = blockIdx.y;
  int g = c >> 6;
  __shared__ __align__(16) short vpl[TD * HWD];  // 32 KB
  __shared__ float at[256];
  int tid = threadIdx.x;
  at[tid] = attn[(size_t)(b * NH + g) * 256 + tid];
  #pragma unroll
  for (int j = 0; j < 8; ++j) {
    int chunk = j * 256 + tid;
    int t = chunk >> 7, qc = chunk & 127;
    bf16x8 v = *(const bf16x8*)&vp[((size_t)(b * TD + t) * CDIM + c) * HWD + qc * 8];
    *(bf16x8*)&vpl[t * HWD + qc * 8] = v;
  }
  __syncthreads();
  int p = tid * 4;
  #pragma unroll
  for (int sh = 0; sh < 2; ++sh) {
    f32x4 acc[8] = {};
    #pragma unroll
    for (int t = 0; t < TD; ++t) {
      bf16x4 v4 = *(const bf16x4*)&vpl[t * HWD + p];
      f32x4 vf = {bf2f(v4[0]), bf2f(v4[1]), bf2f(v4[2]), bf2f(v4[3])};
      #pragma unroll
      for (int s8 = 0; s8 < 8; ++s8) {
        float a = at[(sh * 8 + s8) * 16 + t];
        acc[s8] += a * vf;
      }
    }
    #pragma unroll
    for (int s8 = 0; s8 < 8; ++s8) {
      int s = sh * 8 + s8;
      *(f32x4*)&out[((size_t)(b * TD + s) * CDIM + c) * HWD + p] = acc[s8];
    }
  }
}

// ---------------- launch ----------------
extern "C" void kernel_launch(void* const* d_in, const int* in_sizes, int n_in,
                              void* d_out, int out_size, void* d_ws, size_t ws_size,
                              hipStream_t stream) {
  const float* x   = (const float*)d_in[0];
  const float* lnw = (const float*)d_in[1];
  const float* lnb = (const float*)d_in[2];
  const float* Wq  = (const float*)d_in[3];
  const float* Wk  = (const float*)d_in[4];
  const float* Wv  = (const float*)d_in[5];
  float* out = (float*)d_out;

  char* ws = (char*)d_ws;
  const size_t XNT_OFF   = 0;                       // bf16 [32][1024 q][1024 c]  64 MiB
  const size_t VP_OFF    = XNT_OFF + 67108864;      // bf16 [32][1024 c][1024 q]  64 MiB
  const size_t WB_OFF    = VP_OFF + 67108864;       // bf16 Wv                    2 MiB
  const size_t WQKB_OFF  = WB_OFF + 2097152;        // bf16 [Wq;Wk]               4 MiB
  const size_t POOLB_OFF = WQKB_OFF + 4194304;      // bf16 [32][1024]
  const size_t QM_OFF    = POOLB_OFF + 65536;
  const size_t KM_OFF    = QM_OFF + 131072;
  const size_t ATTN_OFF  = KM_OFF + 131072;         // f32 [32][16][16]

  short* xnT    = (short*)(ws + XNT_OFF);
  short* vp     = (short*)(ws + VP_OFF);
  // pool partials alias the vp region: written by k_ln_t, consumed by
  // k_pool_red, both strictly before k_vgemm writes vp (stream-ordered).
  float* poolp  = (float*)(ws + VP_OFF);            // f32 [32][64][1024] = 8 MiB
  short* Wb     = (short*)(ws + WB_OFF);
  short* Wqkb   = (short*)(ws + WQKB_OFF);
  short* poolb  = (short*)(ws + POOLB_OFF);
  float* qm     = (float*)(ws + QM_OFF);
  float* km     = (float*)(ws + KM_OFF);
  float* attn   = (float*)(ws + ATTN_OFF);

  k_cast_w<<<dim3(1024), 256, 0, stream>>>(Wv, Wb);
  k_cast_w<<<dim3(1024), 256, 0, stream>>>(Wq, Wqkb);
  k_cast_w<<<dim3(1024), 256, 0, stream>>>(Wk, Wqkb + 1048576);
  k_ln_t<<<dim3(64, 32), 256, 0, stream>>>(x, lnw, lnb, xnT, poolp);
  k_pool_red<<<dim3(4, 32), 256, 0, stream>>>(poolp, poolb);
  k_qk_mfma<<<dim3(16), 256, 0, stream>>>(Wqkb, poolb, qm, km);
  k_attn<<<dim3(32), 256, 0, stream>>>(qm, km, attn);
  k_vgemm<<<dim3(512), 512, 0, stream>>>(Wb, xnT, vp);
  k_mix<<<dim3(1024, 2), 256, 0, stream>>>(vp, attn, out);
}

// Round 7
// 252.348 us; speedup vs baseline: 1.0981x; 1.0981x over previous
//
#include <hip/hip_runtime.h>
#include <stdint.h>
#include <stddef.h>

#define CDIM 1024
#define HWD  1024   // 32*32
#define TD   16
#define BD   2
#define NH   16
#define DHD  64

typedef __attribute__((ext_vector_type(8))) short bf16x8;
typedef __attribute__((ext_vector_type(4))) short bf16x4;
typedef __attribute__((ext_vector_type(4))) float f32x4;

static __device__ __forceinline__ short f2bf(float f) {
  uint32_t u = __builtin_bit_cast(uint32_t, f);
  uint32_t r = (u + 0x7FFFu + ((u >> 16) & 1u)) >> 16;
  return (short)(uint16_t)r;
}
static __device__ __forceinline__ float bf2f(short s) {
  return __builtin_bit_cast(float, (uint32_t)((uint16_t)s) << 16);
}

static __device__ __forceinline__ void gl_lds16(const short* g, short* l) {
  __builtin_amdgcn_global_load_lds((const __attribute__((address_space(1))) unsigned int*)g,
                                   (__attribute__((address_space(3))) unsigned int*)l,
                                   16, 0, 0);
}

// ---------------- K0: cast Wq|Wk|Wv -> bf16 (fused, one launch) ----------------
__global__ void k_cast3(const float* __restrict__ Wq, const float* __restrict__ Wk,
                        const float* __restrict__ Wv, short* __restrict__ Wqkb,
                        short* __restrict__ Wb) {
  int bid = blockIdx.x;                         // 0..3071
  int mat = bid >> 10;                          // 0:Wq 1:Wk 2:Wv
  const float* src = mat == 0 ? Wq : (mat == 1 ? Wk : Wv);
  short* dst = mat == 0 ? Wqkb : (mat == 1 ? Wqkb + 1048576 : Wb);
  int i = ((bid & 1023) * 256 + threadIdx.x) * 4;
  f32x4 v = *(const f32x4*)&src[i];
  dst[i + 0] = f2bf(v[0]);
  dst[i + 1] = f2bf(v[1]);
  dst[i + 2] = f2bf(v[2]);
  dst[i + 3] = f2bf(v[3]);
}

// ---------------- K1: LayerNorm over C + transposed bf16 write + pool partials ----
// 16-pixel blocks, grid (64, 32) = 2048 blocks -> high occupancy.
__global__ __launch_bounds__(256) void k_ln_t(const float* __restrict__ x,
                                              const float* __restrict__ lnw,
                                              const float* __restrict__ lnb,
                                              short* __restrict__ xnT,
                                              float* __restrict__ part) {
  int bt = blockIdx.y;
  int p0 = blockIdx.x * 16;
  int tid = threadIdx.x;
  int pg = tid & 3, cs = tid >> 2;
  int pbase = p0 + pg * 4;
  const float* xs = x + (size_t)bt * CDIM * HWD;

  // ---- pass 1: per-pixel sum / sumsq over C
  float s[4] = {}, s2[4] = {};
  #pragma unroll
  for (int j = 0; j < 16; ++j) {
    int c = cs + 64 * j;
    f32x4 v = *(const f32x4*)&xs[(size_t)c * HWD + pbase];
    #pragma unroll
    for (int i = 0; i < 4; ++i) { s[i] += v[i]; s2[i] += v[i] * v[i]; }
  }
  __shared__ float redA[64][16], redB[64][16];
  #pragma unroll
  for (int i = 0; i < 4; ++i) {
    redA[cs][pg * 4 + i] = s[i];
    redB[cs][pg * 4 + i] = s2[i];
  }
  __syncthreads();
  __shared__ float muS[16], rsS[16];
  if (tid < 16) {
    float a = 0.f, b2 = 0.f;
    for (int k = 0; k < 64; ++k) { a += redA[k][tid]; b2 += redB[k][tid]; }
    float mu = a * (1.0f / CDIM);
    float var = b2 * (1.0f / CDIM) - mu * mu;
    muS[tid] = mu;
    rsS[tid] = rsqrtf(var + 1e-5f);
  }
  __syncthreads();
  float mu_[4], rs_[4];
  #pragma unroll
  for (int i = 0; i < 4; ++i) { mu_[i] = muS[pg * 4 + i]; rs_[i] = rsS[pg * 4 + i]; }

  // ---- pass 2: normalize (L2/L3-hit), transpose via LDS, pool partials
  __shared__ short tile[16 * 272];
  __shared__ float pr[256][4];
  short* outB = xnT + (size_t)bt * CDIM * HWD;

  for (int cb = 0; cb < 4; ++cb) {
    #pragma unroll
    for (int jj = 0; jj < 4; ++jj) {
      int cl = cs * 4 + jj;
      int c = cb * 256 + cl;
      f32x4 v = *(const f32x4*)&xs[(size_t)c * HWD + pbase];
      float w = lnw[c], bb = lnb[c];
      float psum = 0.f;
      #pragma unroll
      for (int i = 0; i < 4; ++i) {
        float xn = (v[i] - mu_[i]) * rs_[i] * w + bb;
        tile[(pg * 4 + i) * 272 + cl] = f2bf(xn);
        psum += xn;
      }
      pr[cl][pg] = psum;
    }
    __syncthreads();
    #pragma unroll
    for (int it = 0; it < 2; ++it) {
      int ch = it * 256 + tid;
      int plo = ch >> 5;
      int c8 = (ch & 31) * 8;
      bf16x8 vv = *(const bf16x8*)&tile[plo * 272 + c8];
      int pq = p0 + plo;
      int q = (pq & 31) * 32 + (pq >> 5);   // 32x32 spatial transpose
      *(bf16x8*)&outB[(size_t)q * CDIM + cb * 256 + c8] = vv;
    }
    {
      float a = pr[tid][0] + pr[tid][1] + pr[tid][2] + pr[tid][3];
      part[((size_t)bt * 64 + blockIdx.x) * CDIM + cb * 256 + tid] = a;
    }
    __syncthreads();
  }
}

// ---------------- K2: pooled(bf16) = mean over pixels (reduce 64 partials) ------
__global__ void k_pool_red(const float* __restrict__ part, short* __restrict__ pooledb) {
  int bt = blockIdx.y;
  int c = blockIdx.x * 256 + threadIdx.x;
  float s = 0.f;
  #pragma unroll
  for (int pc = 0; pc < 64; ++pc) s += part[((size_t)bt * 64 + pc) * CDIM + c];
  pooledb[bt * CDIM + c] = f2bf(s * (1.0f / HWD));
}

// ---------------- K3: q|k = pooled @ [Wq;Wk]^T via MFMA ----------------
__global__ __launch_bounds__(256) void k_qk_mfma(const short* __restrict__ Wqkb,
                                                 const short* __restrict__ pooledb,
                                                 float* __restrict__ qm,
                                                 float* __restrict__ km) {
  int n0 = blockIdx.x * 128;
  __shared__ __align__(16) short lA[32 * 32];
  __shared__ __align__(16) short lB[128 * 32];
  int tid = threadIdx.x, lane = tid & 63, wid = tid >> 6;
  int s0 = wid * 128 + lane, s1 = s0 + 64;
  int fr = lane & 15, fk = (lane >> 4) * 8;
  f32x4 acc[2][2] = {};

  for (int kt = 0; kt < CDIM / 32; ++kt) {
    int k0 = kt * 32;
    __syncthreads();
    gl_lds16(&Wqkb[(size_t)(n0 + (s0 >> 2)) * CDIM + k0 + (s0 & 3) * 8], &lB[s0 * 8]);
    gl_lds16(&Wqkb[(size_t)(n0 + (s1 >> 2)) * CDIM + k0 + (s1 & 3) * 8], &lB[s1 * 8]);
    if (wid < 2) {
      gl_lds16(&pooledb[(size_t)(tid >> 2) * CDIM + k0 + (tid & 3) * 8], &lA[tid * 8]);
    }
    __syncthreads();
    bf16x8 af[2], bfr[2];
    #pragma unroll
    for (int mi = 0; mi < 2; ++mi)
      af[mi] = *(const bf16x8*)&lA[(mi * 16 + fr) * 32 + fk];
    #pragma unroll
    for (int ni = 0; ni < 2; ++ni)
      bfr[ni] = *(const bf16x8*)&lB[(wid * 32 + ni * 16 + fr) * 32 + fk];
    #pragma unroll
    for (int mi = 0; mi < 2; ++mi)
      #pragma unroll
      for (int ni = 0; ni < 2; ++ni)
        acc[mi][ni] = __builtin_amdgcn_mfma_f32_16x16x32_bf16(af[mi], bfr[ni], acc[mi][ni], 0, 0, 0);
  }

  int cr = lane >> 4;
  #pragma unroll
  for (int mi = 0; mi < 2; ++mi)
    #pragma unroll
    for (int ni = 0; ni < 2; ++ni)
      #pragma unroll
      for (int rr = 0; rr < 4; ++rr) {
        int row = mi * 16 + cr * 4 + rr;
        int col = n0 + wid * 32 + ni * 16 + fr;
        float v = acc[mi][ni][rr];
        if (col < 1024) qm[(size_t)row * CDIM + col] = v;
        else            km[(size_t)row * CDIM + col - 1024] = v;
      }
}

// ---------------- K4: attention softmax ----------------
__global__ void k_attn(const float* __restrict__ qm, const float* __restrict__ km,
                       float* __restrict__ attn) {
  int bg = blockIdx.x;
  int b = bg >> 4, g = bg & 15;
  int s = threadIdx.x >> 4, t = threadIdx.x & 15;
  const float* qr = qm + (size_t)(b * TD + s) * CDIM + g * DHD;
  const float* kr = km + (size_t)(b * TD + t) * CDIM + g * DHD;
  float d = 0.f;
  #pragma unroll
  for (int i = 0; i < DHD; ++i) d += qr[i] * kr[i];
  d *= 0.125f;
  float m = d;
  #pragma unroll
  for (int off = 8; off; off >>= 1) m = fmaxf(m, __shfl_xor(m, off, 16));
  float e = __expf(d - m);
  float sum = e;
  #pragma unroll
  for (int off = 8; off; off >>= 1) sum += __shfl_xor(sum, off, 16);
  attn[(size_t)bg * 256 + s * 16 + t] = e / sum;
}

// ---------------- K5: V-GEMM (R4-v2 revert + front-loaded prefetch) -------------
// vp[bt][c][q] = sum_c' Wv[c,c'] * xnT[bt][q][c']
// 256x256 tile, BK=64, 8 waves (2Mx4N), 128 KiB double-buffered LDS,
// 4 phases/K-tile (16 MFMA each). Change vs R4-v2: all 4 ISSUEs of tile kt+1
// front-loaded into phases 0-1 (newest rendezvous-load is 3 phases old, not 1);
// wait vmcnt(4) once per tile. Swizzle identical to R4-v2 (conflicts measured 0).
__global__ __launch_bounds__(512, 2) void k_vgemm(const short* __restrict__ Wb,
                                                  const short* __restrict__ xnT,
                                                  short* __restrict__ vp) {
  int bid = blockIdx.x;
  int swz = (bid & 7) * 64 + (bid >> 3);   // bijective XCD swizzle (512%8==0)
  int bt = swz >> 4;
  int m0 = ((swz >> 2) & 3) * 256;
  int n0 = (swz & 3) * 256;
  const short* Bm = xnT + (size_t)bt * CDIM * HWD;

  __shared__ __align__(16) short lA[2][256 * 64];   // 2 x 32 KB
  __shared__ __align__(16) short lB[2][256 * 64];   // 2 x 32 KB

  int tid = threadIdx.x, lane = tid & 63, wid = tid >> 6;
  int wm = wid >> 2, wn = wid & 3;   // wave tile: 128(M) x 64(N)

  int srow = wid * 8 + (lane >> 3);
  int schunk = (lane & 7) ^ (lane >> 3);
  const short* gA = Wb + (size_t)(m0 + srow) * CDIM + schunk * 8;
  const short* gB = Bm + (size_t)(n0 + srow) * CDIM + schunk * 8;
  int doff = wid * 512 + lane * 8;

  int fr = lane & 15, klane = lane >> 4;
  int c0 = ((klane ^ (fr & 7)) * 8);
  int rA = (wm * 128 + fr) * 64;
  int rB = (wn * 64 + fr) * 64;

  f32x4 acc[8][4] = {};
  bf16x8 bq[4], af[4];

#define ISSUE(p, kt1, nb)                                                      \
  do {                                                                         \
    gl_lds16(gA + (size_t)(p) * 64 * CDIM + (kt1) * 64, &lA[nb][(p) * 4096 + doff]); \
    gl_lds16(gB + (size_t)(p) * 64 * CDIM + (kt1) * 64, &lB[nb][(p) * 4096 + doff]); \
  } while (0)
#define RDA(mi, ks, b) (*(const bf16x8*)&lA[b][rA + (mi) * 1024 + (c0 ^ ((ks) * 32))])
#define RDB(ni, ks, b) (*(const bf16x8*)&lB[b][rB + (ni) * 1024 + (c0 ^ ((ks) * 32))])

  // prologue: stage tile 0 into buf 0
  ISSUE(0, 0, 0); ISSUE(1, 0, 0); ISSUE(2, 0, 0); ISSUE(3, 0, 0);

  for (int kt = 0; kt < 16; ++kt) {
    int cur = kt & 1, nxt = cur ^ 1;
    bool st = (kt + 1 < 16);
    // ---- phase 0: prefetch half of kt+1, rendezvous on tile kt
    if (st) {
      ISSUE(0, kt + 1, nxt); ISSUE(1, kt + 1, nxt);
      asm volatile("s_waitcnt vmcnt(4)" ::: "memory");
    } else {
      asm volatile("s_waitcnt vmcnt(0)" ::: "memory");
    }
    __builtin_amdgcn_s_barrier();
    #pragma unroll
    for (int ni = 0; ni < 4; ++ni) bq[ni] = RDB(ni, 0, cur);
    #pragma unroll
    for (int mi = 0; mi < 4; ++mi) af[mi] = RDA(mi, 0, cur);
    __builtin_amdgcn_s_setprio(1);
    #pragma unroll
    for (int mi = 0; mi < 4; ++mi)
      #pragma unroll
      for (int ni = 0; ni < 4; ++ni)
        acc[mi][ni] = __builtin_amdgcn_mfma_f32_16x16x32_bf16(af[mi], bq[ni], acc[mi][ni], 0, 0, 0);
    __builtin_amdgcn_s_setprio(0);
    __builtin_amdgcn_s_barrier();
    // ---- phase 1: quad (mh=1, ks=0); second half of kt+1 prefetch
    #pragma unroll
    for (int mi = 0; mi < 4; ++mi) af[mi] = RDA(4 + mi, 0, cur);
    if (st) { ISSUE(2, kt + 1, nxt); ISSUE(3, kt + 1, nxt); }
    __builtin_amdgcn_s_barrier();
    __builtin_amdgcn_s_setprio(1);
    #pragma unroll
    for (int mi = 0; mi < 4; ++mi)
      #pragma unroll
      for (int ni = 0; ni < 4; ++ni)
        acc[4 + mi][ni] = __builtin_amdgcn_mfma_f32_16x16x32_bf16(af[mi], bq[ni], acc[4 + mi][ni], 0, 0, 0);
    __builtin_amdgcn_s_setprio(0);
    __builtin_amdgcn_s_barrier();
    // ---- phase 2: quad (mh=0, ks=1)
    #pragma unroll
    for (int ni = 0; ni < 4; ++ni) bq[ni] = RDB(ni, 1, cur);
    #pragma unroll
    for (int mi = 0; mi < 4; ++mi) af[mi] = RDA(mi, 1, cur);
    __builtin_amdgcn_s_barrier();
    __builtin_amdgcn_s_setprio(1);
    #pragma unroll
    for (int mi = 0; mi < 4; ++mi)
      #pragma unroll
      for (int ni = 0; ni < 4; ++ni)
        acc[mi][ni] = __builtin_amdgcn_mfma_f32_16x16x32_bf16(af[mi], bq[ni], acc[mi][ni], 0, 0, 0);
    __builtin_amdgcn_s_setprio(0);
    __builtin_amdgcn_s_barrier();
    // ---- phase 3: quad (mh=1, ks=1)
    #pragma unroll
    for (int mi = 0; mi < 4; ++mi) af[mi] = RDA(4 + mi, 1, cur);
    __builtin_amdgcn_s_barrier();
    __builtin_amdgcn_s_setprio(1);
    #pragma unroll
    for (int mi = 0; mi < 4; ++mi)
      #pragma unroll
      for (int ni = 0; ni < 4; ++ni)
        acc[4 + mi][ni] = __builtin_amdgcn_mfma_f32_16x16x32_bf16(af[mi], bq[ni], acc[4 + mi][ni], 0, 0, 0);
    __builtin_amdgcn_s_setprio(0);
    __builtin_amdgcn_s_barrier();
  }
#undef ISSUE
#undef RDA
#undef RDB

  short* outB = vp + (size_t)bt * CDIM * HWD;
  int cr = lane >> 4;
  #pragma unroll
  for (int mi = 0; mi < 8; ++mi)
    #pragma unroll
    for (int ni = 0; ni < 4; ++ni)
      #pragma unroll
      for (int r = 0; r < 4; ++r) {
        int row = m0 + wm * 128 + mi * 16 + cr * 4 + r;   // c
        int col = n0 + wn * 64 + ni * 16 + fr;            // q
        outB[(size_t)row * HWD + col] = f2bf(acc[mi][ni][r]);
      }
}

// ---------------- K6: T-mix ----------------
__global__ __launch_bounds__(256) void k_mix(const short* __restrict__ vp,
                                             const float* __restrict__ attn,
                                             float* __restrict__ out) {
  int c = blockIdx.x;
  int b = blockIdx.y;
  int g = c >> 6;
  __shared__ __align__(16) short vpl[TD * HWD];  // 32 KB
  __shared__ float at[256];
  int tid = threadIdx.x;
  at[tid] = attn[(size_t)(b * NH + g) * 256 + tid];
  #pragma unroll
  for (int j = 0; j < 8; ++j) {
    int chunk = j * 256 + tid;
    int t = chunk >> 7, qc = chunk & 127;
    bf16x8 v = *(const bf16x8*)&vp[((size_t)(b * TD + t) * CDIM + c) * HWD + qc * 8];
    *(bf16x8*)&vpl[t * HWD + qc * 8] = v;
  }
  __syncthreads();
  int p = tid * 4;
  #pragma unroll
  for (int sh = 0; sh < 2; ++sh) {
    f32x4 acc[8] = {};
    #pragma unroll
    for (int t = 0; t < TD; ++t) {
      bf16x4 v4 = *(const bf16x4*)&vpl[t * HWD + p];
      f32x4 vf = {bf2f(v4[0]), bf2f(v4[1]), bf2f(v4[2]), bf2f(v4[3])};
      #pragma unroll
      for (int s8 = 0; s8 < 8; ++s8) {
        float a = at[(sh * 8 + s8) * 16 + t];
        acc[s8] += a * vf;
      }
    }
    #pragma unroll
    for (int s8 = 0; s8 < 8; ++s8) {
      int s = sh * 8 + s8;
      *(f32x4*)&out[((size_t)(b * TD + s) * CDIM + c) * HWD + p] = acc[s8];
    }
  }
}

// ---------------- launch ----------------
extern "C" void kernel_launch(void* const* d_in, const int* in_sizes, int n_in,
                              void* d_out, int out_size, void* d_ws, size_t ws_size,
                              hipStream_t stream) {
  const float* x   = (const float*)d_in[0];
  const float* lnw = (const float*)d_in[1];
  const float* lnb = (const float*)d_in[2];
  const float* Wq  = (const float*)d_in[3];
  const float* Wk  = (const float*)d_in[4];
  const float* Wv  = (const float*)d_in[5];
  float* out = (float*)d_out;

  char* ws = (char*)d_ws;
  const size_t XNT_OFF   = 0;                       // bf16 [32][1024 q][1024 c]  64 MiB
  const size_t VP_OFF    = XNT_OFF + 67108864;      // bf16 [32][1024 c][1024 q]  64 MiB
  const size_t WB_OFF    = VP_OFF + 67108864;       // bf16 Wv                    2 MiB
  const size_t WQKB_OFF  = WB_OFF + 2097152;        // bf16 [Wq;Wk]               4 MiB
  const size_t POOLB_OFF = WQKB_OFF + 4194304;      // bf16 [32][1024]
  const size_t QM_OFF    = POOLB_OFF + 65536;
  const size_t KM_OFF    = QM_OFF + 131072;
  const size_t ATTN_OFF  = KM_OFF + 131072;         // f32 [32][16][16]

  short* xnT    = (short*)(ws + XNT_OFF);
  short* vp     = (short*)(ws + VP_OFF);
  // pool partials alias the vp region: written by k_ln_t, consumed by
  // k_pool_red, both strictly before k_vgemm writes vp (stream-ordered).
  float* poolp  = (float*)(ws + VP_OFF);            // f32 [32][64][1024] = 8 MiB
  short* Wb     = (short*)(ws + WB_OFF);
  short* Wqkb   = (short*)(ws + WQKB_OFF);
  short* poolb  = (short*)(ws + POOLB_OFF);
  float* qm     = (float*)(ws + QM_OFF);
  float* km     = (float*)(ws + KM_OFF);
  float* attn   = (float*)(ws + ATTN_OFF);

  k_cast3<<<dim3(3072), 256, 0, stream>>>(Wq, Wk, Wv, Wqkb, Wb);
  k_ln_t<<<dim3(64, 32), 256, 0, stream>>>(x, lnw, lnb, xnT, poolp);
  k_pool_red<<<dim3(4, 32), 256, 0, stream>>>(poolp, poolb);
  k_qk_mfma<<<dim3(16), 256, 0, stream>>>(Wqkb, poolb, qm, km);
  k_attn<<<dim3(32), 256, 0, stream>>>(qm, km, attn);
  k_vgemm<<<dim3(512), 512, 0, stream>>>(Wb, xnT, vp);
  k_mix<<<dim3(1024, 2), 256, 0, stream>>>(vp, attn, out);
}

// Round 8
// 239.181 us; speedup vs baseline: 1.1586x; 1.0551x over previous
//
#include <hip/hip_runtime.h>
#include <stdint.h>
#include <stddef.h>

#define CDIM 1024
#define HWD  1024   // 32*32
#define TD   16
#define BD   2
#define NH   16
#define DHD  64

typedef __attribute__((ext_vector_type(8))) short bf16x8;
typedef __attribute__((ext_vector_type(4))) short bf16x4;
typedef __attribute__((ext_vector_type(4))) float f32x4;

static __device__ __forceinline__ short f2bf(float f) {
  uint32_t u = __builtin_bit_cast(uint32_t, f);
  uint32_t r = (u + 0x7FFFu + ((u >> 16) & 1u)) >> 16;
  return (short)(uint16_t)r;
}
static __device__ __forceinline__ float bf2f(short s) {
  return __builtin_bit_cast(float, (uint32_t)((uint16_t)s) << 16);
}

static __device__ __forceinline__ void gl_lds16(const short* g, short* l) {
  __builtin_amdgcn_global_load_lds((const __attribute__((address_space(1))) unsigned int*)g,
                                   (__attribute__((address_space(3))) unsigned int*)l,
                                   16, 0, 0);
}

// ---------------- K0: cast Wq|Wk|Wv -> bf16 (fused, one launch) ----------------
__global__ void k_cast3(const float* __restrict__ Wq, const float* __restrict__ Wk,
                        const float* __restrict__ Wv, short* __restrict__ Wqkb,
                        short* __restrict__ Wb) {
  int bid = blockIdx.x;                         // 0..3071
  int mat = bid >> 10;                          // 0:Wq 1:Wk 2:Wv
  const float* src = mat == 0 ? Wq : (mat == 1 ? Wk : Wv);
  short* dst = mat == 0 ? Wqkb : (mat == 1 ? Wqkb + 1048576 : Wb);
  int i = ((bid & 1023) * 256 + threadIdx.x) * 4;
  f32x4 v = *(const f32x4*)&src[i];
  dst[i + 0] = f2bf(v[0]);
  dst[i + 1] = f2bf(v[1]);
  dst[i + 2] = f2bf(v[2]);
  dst[i + 3] = f2bf(v[3]);
}

// ---------------- K1a: LN stats partials (contiguous full-row reads) ------------
// grid (32 c-splits, 32 bt), block 1024. Block reads 32 full c-rows (128 KB
// contiguous). partials[bt][split][0|1][1024 px] = sum / sumsq over 32 c.
__global__ __launch_bounds__(1024) void k_ln_stats(const float* __restrict__ x,
                                                   float* __restrict__ partials) {
  int bt = blockIdx.y;
  int c0 = blockIdx.x * 32;
  int tid = threadIdx.x;
  int quad = tid & 255, rowoff = tid >> 8;      // px-quad, row-group
  const float* xs = x + (size_t)bt * CDIM * HWD;

  float s[4] = {}, s2[4] = {};
  #pragma unroll
  for (int j = 0; j < 8; ++j) {
    int c = c0 + rowoff + 4 * j;
    f32x4 v = *(const f32x4*)&xs[(size_t)c * HWD + quad * 4];
    #pragma unroll
    for (int i = 0; i < 4; ++i) { s[i] += v[i]; s2[i] += v[i] * v[i]; }
  }
  __shared__ float redA[4][1024], redB[4][1024];
  #pragma unroll
  for (int i = 0; i < 4; ++i) {
    redA[rowoff][quad * 4 + i] = s[i];
    redB[rowoff][quad * 4 + i] = s2[i];
  }
  __syncthreads();
  int px = tid;
  float a  = redA[0][px] + redA[1][px] + redA[2][px] + redA[3][px];
  float b2 = redB[0][px] + redB[1][px] + redB[2][px] + redB[3][px];
  float* pb = partials + ((size_t)(bt * 32 + blockIdx.x) * 2) * HWD;
  pb[px] = a;
  pb[HWD + px] = b2;
}

// ---------------- K1b: LN stats finish -----------------------------------------
// grid (4, 32 bt), block 256. stats[bt][0][px]=mu, [1][px]=rstd.
__global__ void k_ln_fin(const float* __restrict__ partials, float* __restrict__ stats) {
  int bt = blockIdx.y;
  int px = blockIdx.x * 256 + threadIdx.x;
  float a = 0.f, b2 = 0.f;
  #pragma unroll
  for (int sp = 0; sp < 32; ++sp) {
    const float* pb = partials + ((size_t)(bt * 32 + sp) * 2) * HWD;
    a += pb[px];
    b2 += pb[HWD + px];
  }
  float mu = a * (1.0f / CDIM);
  float var = b2 * (1.0f / CDIM) - mu * mu;
  stats[(size_t)bt * 2 * HWD + px] = mu;
  stats[(size_t)bt * 2 * HWD + HWD + px] = rsqrtf(var + 1e-5f);
}

// ---------------- K1c: normalize + transpose + pool partials -------------------
// grid (32 px-groups, 32 bt), block 256. Block owns 32 pixel-columns x all C,
// processed in 2 c-halves of 512. x re-read is L3-resident (134 MB < 256 MB).
// Writes xnT[q][c] with q = qr*32 + pg (the net 32x32 spatial transpose),
// 128 B sequential per thread. LDS tile XOR-swizzled; read side conflict-free.
__global__ __launch_bounds__(256) void k_ln_norm(const float* __restrict__ x,
                                                 const float* __restrict__ lnw,
                                                 const float* __restrict__ lnb,
                                                 const float* __restrict__ stats,
                                                 short* __restrict__ xnT,
                                                 float* __restrict__ part) {
  int bt = blockIdx.y;
  int pg = blockIdx.x;
  int P0 = pg * 32;
  int tid = threadIdx.x;
  int pq = tid & 7, rowgrp = tid >> 3;          // px-quad (4 px), c-row group
  const float* xs = x + (size_t)bt * CDIM * HWD;
  short* outB = xnT + (size_t)bt * CDIM * HWD;

  // per-thread pixel stats (4 px fixed)
  f32x4 mu4 = *(const f32x4*)&stats[(size_t)bt * 2 * HWD + P0 + pq * 4];
  f32x4 rs4 = *(const f32x4*)&stats[(size_t)bt * 2 * HWD + HWD + P0 + pq * 4];

  __shared__ short tile[32 * 514];              // [32 px][512 c] swizzled, odd-dword stride
  __shared__ float prA[512][8];                 // pool partials [c_local][pq]

  for (int ch = 0; ch < 2; ++ch) {
    // ---- read + normalize + LDS store (scalar b16, swizzled) + pool partial
    #pragma unroll
    for (int j = 0; j < 16; ++j) {
      int cl = rowgrp + 32 * j;                 // c_local 0..511
      int c = ch * 512 + cl;
      f32x4 v = *(const f32x4*)&xs[(size_t)c * HWD + P0 + pq * 4];
      float w = lnw[c], bb = lnb[c];
      int cc = cl >> 3, c7 = cl & 7;
      float psum = 0.f;
      #pragma unroll
      for (int i = 0; i < 4; ++i) {
        int px = pq * 4 + i;
        float xn = (v[i] - mu4[i]) * rs4[i] * w + bb;
        psum += xn;
        tile[px * 514 + ((cc ^ (px & 7)) << 3) + c7] = f2bf(xn);
      }
      prA[cl][pq] = psum;
    }
    __syncthreads();
    // ---- transposed write: thread = (qr, seg), 64 consecutive c = 128 B
    {
      int qr = tid & 31, seg = tid >> 5;        // q-row in block, c-seg of 64
      int q = qr * 32 + pg;                     // spatial transpose
      short* dst = outB + (size_t)q * CDIM + ch * 512 + seg * 64;
      #pragma unroll
      for (int mm = 0; mm < 8; ++mm) {
        int cc = seg * 8 + mm;
        bf16x8 vv = *(const bf16x8*)&tile[qr * 514 + ((cc ^ (qr & 7)) << 3)];
        *(bf16x8*)&dst[mm * 8] = vv;
      }
    }
    // ---- pool partial reduce (8 quads -> 1) for this c-half
    #pragma unroll
    for (int rep = 0; rep < 2; ++rep) {
      int cl = rep * 256 + tid;
      float a = 0.f;
      #pragma unroll
      for (int k = 0; k < 8; ++k) a += prA[cl][k];
      part[((size_t)(bt * 32 + pg)) * CDIM + ch * 512 + cl] = a;
    }
    __syncthreads();
  }
}

// ---------------- K2: pooled(bf16) = mean over pixels (reduce 32 partials) ------
__global__ void k_pool_red(const float* __restrict__ part, short* __restrict__ pooledb) {
  int bt = blockIdx.y;
  int c = blockIdx.x * 256 + threadIdx.x;
  float s = 0.f;
  #pragma unroll
  for (int pc = 0; pc < 32; ++pc) s += part[((size_t)(bt * 32 + pc)) * CDIM + c];
  pooledb[bt * CDIM + c] = f2bf(s * (1.0f / HWD));
}

// ---------------- K3: q|k = pooled @ [Wq;Wk]^T via MFMA ----------------
__global__ __launch_bounds__(256) void k_qk_mfma(const short* __restrict__ Wqkb,
                                                 const short* __restrict__ pooledb,
                                                 float* __restrict__ qm,
                                                 float* __restrict__ km) {
  int n0 = blockIdx.x * 128;
  __shared__ __align__(16) short lA[32 * 32];
  __shared__ __align__(16) short lB[128 * 32];
  int tid = threadIdx.x, lane = tid & 63, wid = tid >> 6;
  int s0 = wid * 128 + lane, s1 = s0 + 64;
  int fr = lane & 15, fk = (lane >> 4) * 8;
  f32x4 acc[2][2] = {};

  for (int kt = 0; kt < CDIM / 32; ++kt) {
    int k0 = kt * 32;
    __syncthreads();
    gl_lds16(&Wqkb[(size_t)(n0 + (s0 >> 2)) * CDIM + k0 + (s0 & 3) * 8], &lB[s0 * 8]);
    gl_lds16(&Wqkb[(size_t)(n0 + (s1 >> 2)) * CDIM + k0 + (s1 & 3) * 8], &lB[s1 * 8]);
    if (wid < 2) {
      gl_lds16(&pooledb[(size_t)(tid >> 2) * CDIM + k0 + (tid & 3) * 8], &lA[tid * 8]);
    }
    __syncthreads();
    bf16x8 af[2], bfr[2];
    #pragma unroll
    for (int mi = 0; mi < 2; ++mi)
      af[mi] = *(const bf16x8*)&lA[(mi * 16 + fr) * 32 + fk];
    #pragma unroll
    for (int ni = 0; ni < 2; ++ni)
      bfr[ni] = *(const bf16x8*)&lB[(wid * 32 + ni * 16 + fr) * 32 + fk];
    #pragma unroll
    for (int mi = 0; mi < 2; ++mi)
      #pragma unroll
      for (int ni = 0; ni < 2; ++ni)
        acc[mi][ni] = __builtin_amdgcn_mfma_f32_16x16x32_bf16(af[mi], bfr[ni], acc[mi][ni], 0, 0, 0);
  }

  int cr = lane >> 4;
  #pragma unroll
  for (int mi = 0; mi < 2; ++mi)
    #pragma unroll
    for (int ni = 0; ni < 2; ++ni)
      #pragma unroll
      for (int rr = 0; rr < 4; ++rr) {
        int row = mi * 16 + cr * 4 + rr;
        int col = n0 + wid * 32 + ni * 16 + fr;
        float v = acc[mi][ni][rr];
        if (col < 1024) qm[(size_t)row * CDIM + col] = v;
        else            km[(size_t)row * CDIM + col - 1024] = v;
      }
}

// ---------------- K4: attention softmax ----------------
__global__ void k_attn(const float* __restrict__ qm, const float* __restrict__ km,
                       float* __restrict__ attn) {
  int bg = blockIdx.x;
  int b = bg >> 4, g = bg & 15;
  int s = threadIdx.x >> 4, t = threadIdx.x & 15;
  const float* qr = qm + (size_t)(b * TD + s) * CDIM + g * DHD;
  const float* kr = km + (size_t)(b * TD + t) * CDIM + g * DHD;
  float d = 0.f;
  #pragma unroll
  for (int i = 0; i < DHD; ++i) d += qr[i] * kr[i];
  d *= 0.125f;
  float m = d;
  #pragma unroll
  for (int off = 8; off; off >>= 1) m = fmaxf(m, __shfl_xor(m, off, 16));
  float e = __expf(d - m);
  float sum = e;
  #pragma unroll
  for (int off = 8; off; off >>= 1) sum += __shfl_xor(sum, off, 16);
  attn[(size_t)bg * 256 + s * 16 + t] = e / sum;
}

// ---------------- K5: V-GEMM — exact R4-v2 (best measured: 93.3 us) -------------
// vp[bt][c][q] = sum_c' Wv[c,c'] * xnT[bt][q][c']
// 256x256 tile, BK=64, 8 waves (2Mx4N), 128 KiB double-buffered LDS,
// 4 phases/K-tile, 1 ISSUE per phase staggered, vmcnt(2) once per tile.
__global__ __launch_bounds__(512, 2) void k_vgemm(const short* __restrict__ Wb,
                                                  const short* __restrict__ xnT,
                                                  short* __restrict__ vp) {
  int bid = blockIdx.x;
  int swz = (bid & 7) * 64 + (bid >> 3);   // bijective XCD swizzle (512%8==0)
  int bt = swz >> 4;
  int m0 = ((swz >> 2) & 3) * 256;
  int n0 = (swz & 3) * 256;
  const short* Bm = xnT + (size_t)bt * CDIM * HWD;

  __shared__ __align__(16) short lA[2][256 * 64];   // 2 x 32 KB
  __shared__ __align__(16) short lB[2][256 * 64];   // 2 x 32 KB

  int tid = threadIdx.x, lane = tid & 63, wid = tid >> 6;
  int wm = wid >> 2, wn = wid & 3;   // wave tile: 128(M) x 64(N)

  int srow = wid * 8 + (lane >> 3);
  int schunk = (lane & 7) ^ (lane >> 3);
  const short* gA = Wb + (size_t)(m0 + srow) * CDIM + schunk * 8;
  const short* gB = Bm + (size_t)(n0 + srow) * CDIM + schunk * 8;
  int doff = wid * 512 + lane * 8;

  int fr = lane & 15, klane = lane >> 4;
  int c0 = ((klane ^ (fr & 7)) * 8);
  int rA = (wm * 128 + fr) * 64;
  int rB = (wn * 64 + fr) * 64;

  f32x4 acc[8][4] = {};
  bf16x8 bq[4], af[4];

#define ISSUE(p, kt1, nb)                                                      \
  do {                                                                         \
    gl_lds16(gA + (size_t)(p) * 64 * CDIM + (kt1) * 64, &lA[nb][(p) * 4096 + doff]); \
    gl_lds16(gB + (size_t)(p) * 64 * CDIM + (kt1) * 64, &lB[nb][(p) * 4096 + doff]); \
  } while (0)
#define RDA(mi, ks, b) (*(const bf16x8*)&lA[b][rA + (mi) * 1024 + (c0 ^ ((ks) * 32))])
#define RDB(ni, ks, b) (*(const bf16x8*)&lB[b][rB + (ni) * 1024 + (c0 ^ ((ks) * 32))])

  // prologue: stage tile 0 into buf 0
  ISSUE(0, 0, 0); ISSUE(1, 0, 0); ISSUE(2, 0, 0); ISSUE(3, 0, 0);

  for (int kt = 0; kt < 16; ++kt) {
    int cur = kt & 1, nxt = cur ^ 1;
    bool st = (kt + 1 < 16);
    // ---- phase 0: quad (mh=0, ks=0); rendezvous on tile kt staging
    if (st) {
      ISSUE(0, kt + 1, nxt);
      asm volatile("s_waitcnt vmcnt(2)" ::: "memory");
    } else {
      asm volatile("s_waitcnt vmcnt(0)" ::: "memory");
    }
    __builtin_amdgcn_s_barrier();
    #pragma unroll
    for (int ni = 0; ni < 4; ++ni) bq[ni] = RDB(ni, 0, cur);
    #pragma unroll
    for (int mi = 0; mi < 4; ++mi) af[mi] = RDA(mi, 0, cur);
    __builtin_amdgcn_s_setprio(1);
    #pragma unroll
    for (int mi = 0; mi < 4; ++mi)
      #pragma unroll
      for (int ni = 0; ni < 4; ++ni)
        acc[mi][ni] = __builtin_amdgcn_mfma_f32_16x16x32_bf16(af[mi], bq[ni], acc[mi][ni], 0, 0, 0);
    __builtin_amdgcn_s_setprio(0);
    __builtin_amdgcn_s_barrier();
    // ---- phase 1: quad (mh=1, ks=0)
    #pragma unroll
    for (int mi = 0; mi < 4; ++mi) af[mi] = RDA(4 + mi, 0, cur);
    if (st) ISSUE(1, kt + 1, nxt);
    __builtin_amdgcn_s_barrier();
    __builtin_amdgcn_s_setprio(1);
    #pragma unroll
    for (int mi = 0; mi < 4; ++mi)
      #pragma unroll
      for (int ni = 0; ni < 4; ++ni)
        acc[4 + mi][ni] = __builtin_amdgcn_mfma_f32_16x16x32_bf16(af[mi], bq[ni], acc[4 + mi][ni], 0, 0, 0);
    __builtin_amdgcn_s_setprio(0);
    __builtin_amdgcn_s_barrier();
    // ---- phase 2: quad (mh=0, ks=1)
    #pragma unroll
    for (int ni = 0; ni < 4; ++ni) bq[ni] = RDB(ni, 1, cur);
    #pragma unroll
    for (int mi = 0; mi < 4; ++mi) af[mi] = RDA(mi, 1, cur);
    if (st) ISSUE(2, kt + 1, nxt);
    __builtin_amdgcn_s_barrier();
    __builtin_amdgcn_s_setprio(1);
    #pragma unroll
    for (int mi = 0; mi < 4; ++mi)
      #pragma unroll
      for (int ni = 0; ni < 4; ++ni)
        acc[mi][ni] = __builtin_amdgcn_mfma_f32_16x16x32_bf16(af[mi], bq[ni], acc[mi][ni], 0, 0, 0);
    __builtin_amdgcn_s_setprio(0);
    __builtin_amdgcn_s_barrier();
    // ---- phase 3: quad (mh=1, ks=1)
    #pragma unroll
    for (int mi = 0; mi < 4; ++mi) af[mi] = RDA(4 + mi, 1, cur);
    if (st) ISSUE(3, kt + 1, nxt);
    __builtin_amdgcn_s_barrier();
    __builtin_amdgcn_s_setprio(1);
    #pragma unroll
    for (int mi = 0; mi < 4; ++mi)
      #pragma unroll
      for (int ni = 0; ni < 4; ++ni)
        acc[4 + mi][ni] = __builtin_amdgcn_mfma_f32_16x16x32_bf16(af[mi], bq[ni], acc[4 + mi][ni], 0, 0, 0);
    __builtin_amdgcn_s_setprio(0);
    __builtin_amdgcn_s_barrier();
  }
#undef ISSUE
#undef RDA
#undef RDB

  short* outB = vp + (size_t)bt * CDIM * HWD;
  int cr = lane >> 4;
  #pragma unroll
  for (int mi = 0; mi < 8; ++mi)
    #pragma unroll
    for (int ni = 0; ni < 4; ++ni)
      #pragma unroll
      for (int r = 0; r < 4; ++r) {
        int row = m0 + wm * 128 + mi * 16 + cr * 4 + r;   // c
        int col = n0 + wn * 64 + ni * 16 + fr;            // q
        outB[(size_t)row * HWD + col] = f2bf(acc[mi][ni][r]);
      }
}

// ---------------- K6: T-mix ----------------
__global__ __launch_bounds__(256) void k_mix(const short* __restrict__ vp,
                                             const float* __restrict__ attn,
                                             float* __restrict__ out) {
  int c = blockIdx.x;
  int b = blockIdx.y;
  int g = c >> 6;
  __shared__ __align__(16) short vpl[TD * HWD];  // 32 KB
  __shared__ float at[256];
  int tid = threadIdx.x;
  at[tid] = attn[(size_t)(b * NH + g) * 256 + tid];
  #pragma unroll
  for (int j = 0; j < 8; ++j) {
    int chunk = j * 256 + tid;
    int t = chunk >> 7, qc = chunk & 127;
    bf16x8 v = *(const bf16x8*)&vp[((size_t)(b * TD + t) * CDIM + c) * HWD + qc * 8];
    *(bf16x8*)&vpl[t * HWD + qc * 8] = v;
  }
  __syncthreads();
  int p = tid * 4;
  #pragma unroll
  for (int sh = 0; sh < 2; ++sh) {
    f32x4 acc[8] = {};
    #pragma unroll
    for (int t = 0; t < TD; ++t) {
      bf16x4 v4 = *(const bf16x4*)&vpl[t * HWD + p];
      f32x4 vf = {bf2f(v4[0]), bf2f(v4[1]), bf2f(v4[2]), bf2f(v4[3])};
      #pragma unroll
      for (int s8 = 0; s8 < 8; ++s8) {
        float a = at[(sh * 8 + s8) * 16 + t];
        acc[s8] += a * vf;
      }
    }
    #pragma unroll
    for (int s8 = 0; s8 < 8; ++s8) {
      int s = sh * 8 + s8;
      *(f32x4*)&out[((size_t)(b * TD + s) * CDIM + c) * HWD + p] = acc[s8];
    }
  }
}

// ---------------- launch ----------------
extern "C" void kernel_launch(void* const* d_in, const int* in_sizes, int n_in,
                              void* d_out, int out_size, void* d_ws, size_t ws_size,
                              hipStream_t stream) {
  const float* x   = (const float*)d_in[0];
  const float* lnw = (const float*)d_in[1];
  const float* lnb = (const float*)d_in[2];
  const float* Wq  = (const float*)d_in[3];
  const float* Wk  = (const float*)d_in[4];
  const float* Wv  = (const float*)d_in[5];
  float* out = (float*)d_out;

  char* ws = (char*)d_ws;
  const size_t XNT_OFF   = 0;                       // bf16 [32][1024 q][1024 c]  64 MiB
  const size_t VP_OFF    = XNT_OFF + 67108864;      // bf16 [32][1024 c][1024 q]  64 MiB
  const size_t WB_OFF    = VP_OFF + 67108864;       // bf16 Wv                    2 MiB
  const size_t WQKB_OFF  = WB_OFF + 2097152;        // bf16 [Wq;Wk]               4 MiB
  const size_t POOLB_OFF = WQKB_OFF + 4194304;      // bf16 [32][1024]
  const size_t QM_OFF    = POOLB_OFF + 65536;
  const size_t KM_OFF    = QM_OFF + 131072;
  const size_t ATTN_OFF  = KM_OFF + 131072;         // f32 [32][16][16]

  short* xnT    = (short*)(ws + XNT_OFF);
  short* vp     = (short*)(ws + VP_OFF);
  // LN scratch aliased into the vp region (all consumed before k_vgemm writes vp):
  float* partials = (float*)(ws + VP_OFF);                   // 8 MiB
  float* part     = (float*)(ws + VP_OFF + 8388608);         // 4 MiB (pool partials)
  float* stats    = (float*)(ws + VP_OFF + 8388608 + 4194304); // 256 KiB
  short* Wb     = (short*)(ws + WB_OFF);
  short* Wqkb   = (short*)(ws + WQKB_OFF);
  short* poolb  = (short*)(ws + POOLB_OFF);
  float* qm     = (float*)(ws + QM_OFF);
  float* km     = (float*)(ws + KM_OFF);
  float* attn   = (float*)(ws + ATTN_OFF);

  k_cast3<<<dim3(3072), 256, 0, stream>>>(Wq, Wk, Wv, Wqkb, Wb);
  k_ln_stats<<<dim3(32, 32), 1024, 0, stream>>>(x, partials);
  k_ln_fin<<<dim3(4, 32), 256, 0, stream>>>(partials, stats);
  k_ln_norm<<<dim3(32, 32), 256, 0, stream>>>(x, lnw, lnb, stats, xnT, part);
  k_pool_red<<<dim3(4, 32), 256, 0, stream>>>(part, poolb);
  k_qk_mfma<<<dim3(16), 256, 0, stream>>>(Wqkb, poolb, qm, km);
  k_attn<<<dim3(32), 256, 0, stream>>>(qm, km, attn);
  k_vgemm<<<dim3(512), 512, 0, stream>>>(Wb, xnT, vp);
  k_mix<<<dim3(1024, 2), 256, 0, stream>>>(vp, attn, out);
}

// Round 9
// 195.401 us; speedup vs baseline: 1.4182x; 1.2241x over previous
//
#include <hip/hip_runtime.h>
#include <stdint.h>
#include <stddef.h>

#define CDIM 1024
#define HWD  1024   // 32*32
#define TD   16
#define BD   2
#define NH   16
#define DHD  64

typedef __attribute__((ext_vector_type(8))) short bf16x8;
typedef __attribute__((ext_vector_type(4))) short bf16x4;
typedef __attribute__((ext_vector_type(4))) float f32x4;

static __device__ __forceinline__ short f2bf(float f) {
  uint32_t u = __builtin_bit_cast(uint32_t, f);
  uint32_t r = (u + 0x7FFFu + ((u >> 16) & 1u)) >> 16;
  return (short)(uint16_t)r;
}
static __device__ __forceinline__ float bf2f(short s) {
  return __builtin_bit_cast(float, (uint32_t)((uint16_t)s) << 16);
}

static __device__ __forceinline__ void gl_lds16(const short* g, short* l) {
  __builtin_amdgcn_global_load_lds((const __attribute__((address_space(1))) unsigned int*)g,
                                   (__attribute__((address_space(3))) unsigned int*)l,
                                   16, 0, 0);
}

// ---------------- K0: cast Wq|Wk|Wv -> bf16 (fused, one launch) ----------------
__global__ void k_cast3(const float* __restrict__ Wq, const float* __restrict__ Wk,
                        const float* __restrict__ Wv, short* __restrict__ Wqkb,
                        short* __restrict__ Wb) {
  int bid = blockIdx.x;                         // 0..3071
  int mat = bid >> 10;                          // 0:Wq 1:Wk 2:Wv
  const float* src = mat == 0 ? Wq : (mat == 1 ? Wk : Wv);
  short* dst = mat == 0 ? Wqkb : (mat == 1 ? Wqkb + 1048576 : Wb);
  int i = ((bid & 1023) * 256 + threadIdx.x) * 4;
  f32x4 v = *(const f32x4*)&src[i];
  dst[i + 0] = f2bf(v[0]);
  dst[i + 1] = f2bf(v[1]);
  dst[i + 2] = f2bf(v[2]);
  dst[i + 3] = f2bf(v[3]);
}

// ---------------- K1: SINGLE-PASS LayerNorm + transpose + pool partials --------
// grid (32 pixel-groups, 32 bt), block 256. Block owns 32 pixel-columns x all C.
// x read ONCE into registers (32 x f32x4 per thread = 128 VGPR); per-pixel
// stats via in-block LDS reduce (block has full C -> no partials/fin kernels);
// normalize from regs into the swizzled LDS transpose tile (verified in R8);
// write xnT[q][c] contiguous 128B/thread + pool partials.
__global__ __launch_bounds__(256) void k_ln(const float* __restrict__ x,
                                            const float* __restrict__ lnw,
                                            const float* __restrict__ lnb,
                                            short* __restrict__ xnT,
                                            float* __restrict__ part) {
  int bt = blockIdx.y;
  int pg = blockIdx.x;
  int P0 = pg * 32;
  int tid = threadIdx.x;
  int pq = tid & 7, cr = tid >> 3;              // px-quad (4 px), c-row group 0..31
  const float* xs = x + (size_t)bt * CDIM * HWD;
  short* outB = xnT + (size_t)bt * CDIM * HWD;

  // ---- read x once: thread holds [32 j][4 px], c = cr + 32*j
  f32x4 v[32];
  float s[4] = {}, s2[4] = {};
  #pragma unroll
  for (int j = 0; j < 32; ++j) {
    int c = cr + 32 * j;
    v[j] = *(const f32x4*)&xs[(size_t)c * HWD + P0 + pq * 4];
    #pragma unroll
    for (int i = 0; i < 4; ++i) { s[i] += v[j][i]; s2[i] += v[j][i] * v[j][i]; }
  }
  __shared__ float redA[32][33], redB[32][33];
  #pragma unroll
  for (int i = 0; i < 4; ++i) {
    redA[cr][pq * 4 + i] = s[i];
    redB[cr][pq * 4 + i] = s2[i];
  }
  __syncthreads();
  __shared__ float muS[32], rsS[32];
  if (tid < 32) {
    float a = 0.f, b2 = 0.f;
    #pragma unroll
    for (int k = 0; k < 32; ++k) { a += redA[k][tid]; b2 += redB[k][tid]; }
    float mu = a * (1.0f / CDIM);
    float var = b2 * (1.0f / CDIM) - mu * mu;
    muS[tid] = mu;
    rsS[tid] = rsqrtf(var + 1e-5f);
  }
  __syncthreads();
  float mu_[4], rs_[4];
  #pragma unroll
  for (int i = 0; i < 4; ++i) { mu_[i] = muS[pq * 4 + i]; rs_[i] = rsS[pq * 4 + i]; }

  // ---- normalize from regs, transpose via LDS (2 c-halves), pool partials
  __shared__ short tile[32 * 514];              // swizzled [32 px][512 c]
  __shared__ float prA[512][8];                 // pool partials [c_local][pq]

  #pragma unroll
  for (int ch = 0; ch < 2; ++ch) {
    #pragma unroll
    for (int jj = 0; jj < 16; ++jj) {
      int j = ch * 16 + jj;                     // v index (static after unroll)
      int cl = cr + 32 * jj;                    // c_local 0..511
      int c = ch * 512 + cl;                    // == cr + 32*j
      float w = lnw[c], bb = lnb[c];
      int cc = cl >> 3, c7 = cl & 7;
      float psum = 0.f;
      #pragma unroll
      for (int i = 0; i < 4; ++i) {
        int px = pq * 4 + i;
        float xn = (v[j][i] - mu_[i]) * rs_[i] * w + bb;
        psum += xn;
        tile[px * 514 + ((cc ^ (px & 7)) << 3) + c7] = f2bf(xn);
      }
      prA[cl][pq] = psum;
    }
    __syncthreads();
    // transposed write: thread = (qr, seg), 64 consecutive c = 128 B
    {
      int qr = tid & 31, seg = tid >> 5;
      int q = qr * 32 + pg;                     // spatial transpose
      short* dst = outB + (size_t)q * CDIM + ch * 512 + seg * 64;
      #pragma unroll
      for (int mm = 0; mm < 8; ++mm) {
        int cc = seg * 8 + mm;
        bf16x8 vv = *(const bf16x8*)&tile[qr * 514 + ((cc ^ (qr & 7)) << 3)];
        *(bf16x8*)&dst[mm * 8] = vv;
      }
    }
    // pool partial reduce (8 quads -> 1) for this c-half
    #pragma unroll
    for (int rep = 0; rep < 2; ++rep) {
      int cl = rep * 256 + tid;
      float a = 0.f;
      #pragma unroll
      for (int k = 0; k < 8; ++k) a += prA[cl][k];
      part[((size_t)(bt * 32 + pg)) * CDIM + ch * 512 + cl] = a;
    }
    __syncthreads();
  }
}

// ---------------- K2: pooled(bf16) = mean over pixels (reduce 32 partials) ------
__global__ void k_pool_red(const float* __restrict__ part, short* __restrict__ pooledb) {
  int bt = blockIdx.y;
  int c = blockIdx.x * 256 + threadIdx.x;
  float s = 0.f;
  #pragma unroll
  for (int pc = 0; pc < 32; ++pc) s += part[((size_t)(bt * 32 + pc)) * CDIM + c];
  pooledb[bt * CDIM + c] = f2bf(s * (1.0f / HWD));
}

// ---------------- K3: q|k = pooled @ [Wq;Wk]^T via MFMA ----------------
__global__ __launch_bounds__(256) void k_qk_mfma(const short* __restrict__ Wqkb,
                                                 const short* __restrict__ pooledb,
                                                 float* __restrict__ qm,
                                                 float* __restrict__ km) {
  int n0 = blockIdx.x * 128;
  __shared__ __align__(16) short lA[32 * 32];
  __shared__ __align__(16) short lB[128 * 32];
  int tid = threadIdx.x, lane = tid & 63, wid = tid >> 6;
  int s0 = wid * 128 + lane, s1 = s0 + 64;
  int fr = lane & 15, fk = (lane >> 4) * 8;
  f32x4 acc[2][2] = {};

  for (int kt = 0; kt < CDIM / 32; ++kt) {
    int k0 = kt * 32;
    __syncthreads();
    gl_lds16(&Wqkb[(size_t)(n0 + (s0 >> 2)) * CDIM + k0 + (s0 & 3) * 8], &lB[s0 * 8]);
    gl_lds16(&Wqkb[(size_t)(n0 + (s1 >> 2)) * CDIM + k0 + (s1 & 3) * 8], &lB[s1 * 8]);
    if (wid < 2) {
      gl_lds16(&pooledb[(size_t)(tid >> 2) * CDIM + k0 + (tid & 3) * 8], &lA[tid * 8]);
    }
    __syncthreads();
    bf16x8 af[2], bfr[2];
    #pragma unroll
    for (int mi = 0; mi < 2; ++mi)
      af[mi] = *(const bf16x8*)&lA[(mi * 16 + fr) * 32 + fk];
    #pragma unroll
    for (int ni = 0; ni < 2; ++ni)
      bfr[ni] = *(const bf16x8*)&lB[(wid * 32 + ni * 16 + fr) * 32 + fk];
    #pragma unroll
    for (int mi = 0; mi < 2; ++mi)
      #pragma unroll
      for (int ni = 0; ni < 2; ++ni)
        acc[mi][ni] = __builtin_amdgcn_mfma_f32_16x16x32_bf16(af[mi], bfr[ni], acc[mi][ni], 0, 0, 0);
  }

  int cr = lane >> 4;
  #pragma unroll
  for (int mi = 0; mi < 2; ++mi)
    #pragma unroll
    for (int ni = 0; ni < 2; ++ni)
      #pragma unroll
      for (int rr = 0; rr < 4; ++rr) {
        int row = mi * 16 + cr * 4 + rr;
        int col = n0 + wid * 32 + ni * 16 + fr;
        float v = acc[mi][ni][rr];
        if (col < 1024) qm[(size_t)row * CDIM + col] = v;
        else            km[(size_t)row * CDIM + col - 1024] = v;
      }
}

// ---------------- K4: attention softmax ----------------
__global__ void k_attn(const float* __restrict__ qm, const float* __restrict__ km,
                       float* __restrict__ attn) {
  int bg = blockIdx.x;
  int b = bg >> 4, g = bg & 15;
  int s = threadIdx.x >> 4, t = threadIdx.x & 15;
  const float* qr = qm + (size_t)(b * TD + s) * CDIM + g * DHD;
  const float* kr = km + (size_t)(b * TD + t) * CDIM + g * DHD;
  float d = 0.f;
  #pragma unroll
  for (int i = 0; i < DHD; ++i) d += qr[i] * kr[i];
  d *= 0.125f;
  float m = d;
  #pragma unroll
  for (int off = 8; off; off >>= 1) m = fmaxf(m, __shfl_xor(m, off, 16));
  float e = __expf(d - m);
  float sum = e;
  #pragma unroll
  for (int off = 8; off; off >>= 1) sum += __shfl_xor(sum, off, 16);
  attn[(size_t)bg * 256 + s * 16 + t] = e / sum;
}

// ---------------- K5: V-GEMM — R4-v2, UNTOUCHED (best measured; ±15% env noise) --
__global__ __launch_bounds__(512, 2) void k_vgemm(const short* __restrict__ Wb,
                                                  const short* __restrict__ xnT,
                                                  short* __restrict__ vp) {
  int bid = blockIdx.x;
  int swz = (bid & 7) * 64 + (bid >> 3);   // bijective XCD swizzle (512%8==0)
  int bt = swz >> 4;
  int m0 = ((swz >> 2) & 3) * 256;
  int n0 = (swz & 3) * 256;
  const short* Bm = xnT + (size_t)bt * CDIM * HWD;

  __shared__ __align__(16) short lA[2][256 * 64];   // 2 x 32 KB
  __shared__ __align__(16) short lB[2][256 * 64];   // 2 x 32 KB

  int tid = threadIdx.x, lane = tid & 63, wid = tid >> 6;
  int wm = wid >> 2, wn = wid & 3;   // wave tile: 128(M) x 64(N)

  int srow = wid * 8 + (lane >> 3);
  int schunk = (lane & 7) ^ (lane >> 3);
  const short* gA = Wb + (size_t)(m0 + srow) * CDIM + schunk * 8;
  const short* gB = Bm + (size_t)(n0 + srow) * CDIM + schunk * 8;
  int doff = wid * 512 + lane * 8;

  int fr = lane & 15, klane = lane >> 4;
  int c0 = ((klane ^ (fr & 7)) * 8);
  int rA = (wm * 128 + fr) * 64;
  int rB = (wn * 64 + fr) * 64;

  f32x4 acc[8][4] = {};
  bf16x8 bq[4], af[4];

#define ISSUE(p, kt1, nb)                                                      \
  do {                                                                         \
    gl_lds16(gA + (size_t)(p) * 64 * CDIM + (kt1) * 64, &lA[nb][(p) * 4096 + doff]); \
    gl_lds16(gB + (size_t)(p) * 64 * CDIM + (kt1) * 64, &lB[nb][(p) * 4096 + doff]); \
  } while (0)
#define RDA(mi, ks, b) (*(const bf16x8*)&lA[b][rA + (mi) * 1024 + (c0 ^ ((ks) * 32))])
#define RDB(ni, ks, b) (*(const bf16x8*)&lB[b][rB + (ni) * 1024 + (c0 ^ ((ks) * 32))])

  // prologue: stage tile 0 into buf 0
  ISSUE(0, 0, 0); ISSUE(1, 0, 0); ISSUE(2, 0, 0); ISSUE(3, 0, 0);

  for (int kt = 0; kt < 16; ++kt) {
    int cur = kt & 1, nxt = cur ^ 1;
    bool st = (kt + 1 < 16);
    // ---- phase 0: quad (mh=0, ks=0); rendezvous on tile kt staging
    if (st) {
      ISSUE(0, kt + 1, nxt);
      asm volatile("s_waitcnt vmcnt(2)" ::: "memory");
    } else {
      asm volatile("s_waitcnt vmcnt(0)" ::: "memory");
    }
    __builtin_amdgcn_s_barrier();
    #pragma unroll
    for (int ni = 0; ni < 4; ++ni) bq[ni] = RDB(ni, 0, cur);
    #pragma unroll
    for (int mi = 0; mi < 4; ++mi) af[mi] = RDA(mi, 0, cur);
    __builtin_amdgcn_s_setprio(1);
    #pragma unroll
    for (int mi = 0; mi < 4; ++mi)
      #pragma unroll
      for (int ni = 0; ni < 4; ++ni)
        acc[mi][ni] = __builtin_amdgcn_mfma_f32_16x16x32_bf16(af[mi], bq[ni], acc[mi][ni], 0, 0, 0);
    __builtin_amdgcn_s_setprio(0);
    __builtin_amdgcn_s_barrier();
    // ---- phase 1: quad (mh=1, ks=0)
    #pragma unroll
    for (int mi = 0; mi < 4; ++mi) af[mi] = RDA(4 + mi, 0, cur);
    if (st) ISSUE(1, kt + 1, nxt);
    __builtin_amdgcn_s_barrier();
    __builtin_amdgcn_s_setprio(1);
    #pragma unroll
    for (int mi = 0; mi < 4; ++mi)
      #pragma unroll
      for (int ni = 0; ni < 4; ++ni)
        acc[4 + mi][ni] = __builtin_amdgcn_mfma_f32_16x16x32_bf16(af[mi], bq[ni], acc[4 + mi][ni], 0, 0, 0);
    __builtin_amdgcn_s_setprio(0);
    __builtin_amdgcn_s_barrier();
    // ---- phase 2: quad (mh=0, ks=1)
    #pragma unroll
    for (int ni = 0; ni < 4; ++ni) bq[ni] = RDB(ni, 1, cur);
    #pragma unroll
    for (int mi = 0; mi < 4; ++mi) af[mi] = RDA(mi, 1, cur);
    if (st) ISSUE(2, kt + 1, nxt);
    __builtin_amdgcn_s_barrier();
    __builtin_amdgcn_s_setprio(1);
    #pragma unroll
    for (int mi = 0; mi < 4; ++mi)
      #pragma unroll
      for (int ni = 0; ni < 4; ++ni)
        acc[mi][ni] = __builtin_amdgcn_mfma_f32_16x16x32_bf16(af[mi], bq[ni], acc[mi][ni], 0, 0, 0);
    __builtin_amdgcn_s_setprio(0);
    __builtin_amdgcn_s_barrier();
    // ---- phase 3: quad (mh=1, ks=1)
    #pragma unroll
    for (int mi = 0; mi < 4; ++mi) af[mi] = RDA(4 + mi, 1, cur);
    if (st) ISSUE(3, kt + 1, nxt);
    __builtin_amdgcn_s_barrier();
    __builtin_amdgcn_s_setprio(1);
    #pragma unroll
    for (int mi = 0; mi < 4; ++mi)
      #pragma unroll
      for (int ni = 0; ni < 4; ++ni)
        acc[4 + mi][ni] = __builtin_amdgcn_mfma_f32_16x16x32_bf16(af[mi], bq[ni], acc[4 + mi][ni], 0, 0, 0);
    __builtin_amdgcn_s_setprio(0);
    __builtin_amdgcn_s_barrier();
  }
#undef ISSUE
#undef RDA
#undef RDB

  short* outB = vp + (size_t)bt * CDIM * HWD;
  int cr = lane >> 4;
  #pragma unroll
  for (int mi = 0; mi < 8; ++mi)
    #pragma unroll
    for (int ni = 0; ni < 4; ++ni)
      #pragma unroll
      for (int r = 0; r < 4; ++r) {
        int row = m0 + wm * 128 + mi * 16 + cr * 4 + r;   // c
        int col = n0 + wn * 64 + ni * 16 + fr;            // q
        outB[(size_t)row * HWD + col] = f2bf(acc[mi][ni][r]);
      }
}

// ---------------- K6: T-mix ----------------
__global__ __launch_bounds__(256) void k_mix(const short* __restrict__ vp,
                                             const float* __restrict__ attn,
                                             float* __restrict__ out) {
  int c = blockIdx.x;
  int b = blockIdx.y;
  int g = c >> 6;
  __shared__ __align__(16) short vpl[TD * HWD];  // 32 KB
  __shared__ float at[256];
  int tid = threadIdx.x;
  at[tid] = attn[(size_t)(b * NH + g) * 256 + tid];
  #pragma unroll
  for (int j = 0; j < 8; ++j) {
    int chunk = j * 256 + tid;
    int t = chunk >> 7, qc = chunk & 127;
    bf16x8 v = *(const bf16x8*)&vp[((size_t)(b * TD + t) * CDIM + c) * HWD + qc * 8];
    *(bf16x8*)&vpl[t * HWD + qc * 8] = v;
  }
  __syncthreads();
  int p = tid * 4;
  #pragma unroll
  for (int sh = 0; sh < 2; ++sh) {
    f32x4 acc[8] = {};
    #pragma unroll
    for (int t = 0; t < TD; ++t) {
      bf16x4 v4 = *(const bf16x4*)&vpl[t * HWD + p];
      f32x4 vf = {bf2f(v4[0]), bf2f(v4[1]), bf2f(v4[2]), bf2f(v4[3])};
      #pragma unroll
      for (int s8 = 0; s8 < 8; ++s8) {
        float a = at[(sh * 8 + s8) * 16 + t];
        acc[s8] += a * vf;
      }
    }
    #pragma unroll
    for (int s8 = 0; s8 < 8; ++s8) {
      int s = sh * 8 + s8;
      *(f32x4*)&out[((size_t)(b * TD + s) * CDIM + c) * HWD + p] = acc[s8];
    }
  }
}

// ---------------- launch ----------------
extern "C" void kernel_launch(void* const* d_in, const int* in_sizes, int n_in,
                              void* d_out, int out_size, void* d_ws, size_t ws_size,
                              hipStream_t stream) {
  const float* x   = (const float*)d_in[0];
  const float* lnw = (const float*)d_in[1];
  const float* lnb = (const float*)d_in[2];
  const float* Wq  = (const float*)d_in[3];
  const float* Wk  = (const float*)d_in[4];
  const float* Wv  = (const float*)d_in[5];
  float* out = (float*)d_out;

  char* ws = (char*)d_ws;
  const size_t XNT_OFF   = 0;                       // bf16 [32][1024 q][1024 c]  64 MiB
  const size_t VP_OFF    = XNT_OFF + 67108864;      // bf16 [32][1024 c][1024 q]  64 MiB
  const size_t WB_OFF    = VP_OFF + 67108864;       // bf16 Wv                    2 MiB
  const size_t WQKB_OFF  = WB_OFF + 2097152;        // bf16 [Wq;Wk]               4 MiB
  const size_t POOLB_OFF = WQKB_OFF + 4194304;      // bf16 [32][1024]
  const size_t QM_OFF    = POOLB_OFF + 65536;
  const size_t KM_OFF    = QM_OFF + 131072;
  const size_t ATTN_OFF  = KM_OFF + 131072;         // f32 [32][16][16]

  short* xnT    = (short*)(ws + XNT_OFF);
  short* vp     = (short*)(ws + VP_OFF);
  // pool partials alias the vp region: written by k_ln, consumed by k_pool_red,
  // both strictly before k_vgemm writes vp (stream-ordered).
  float* part   = (float*)(ws + VP_OFF);            // f32 [32][32][1024] = 4 MiB
  short* Wb     = (short*)(ws + WB_OFF);
  short* Wqkb   = (short*)(ws + WQKB_OFF);
  short* poolb  = (short*)(ws + POOLB_OFF);
  float* qm     = (float*)(ws + QM_OFF);
  float* km     = (float*)(ws + KM_OFF);
  float* attn   = (float*)(ws + ATTN_OFF);

  k_cast3<<<dim3(3072), 256, 0, stream>>>(Wq, Wk, Wv, Wqkb, Wb);
  k_ln<<<dim3(32, 32), 256, 0, stream>>>(x, lnw, lnb, xnT, part);
  k_pool_red<<<dim3(4, 32), 256, 0, stream>>>(part, poolb);
  k_qk_mfma<<<dim3(16), 256, 0, stream>>>(Wqkb, poolb, qm, km);
  k_attn<<<dim3(32), 256, 0, stream>>>(qm, km, attn);
  k_vgemm<<<dim3(512), 512, 0, stream>>>(Wb, xnT, vp);
  k_mix<<<dim3(1024, 2), 256, 0, stream>>>(vp, attn, out);
}